// Round 2
// baseline (625.259 us; speedup 1.0000x reference)
//
#include <hip/hip_runtime.h>
#include <hip/hip_bf16.h>

#define BATCH 8
#define NTOK 4096      // H*W per batch
#define CH 256
#define CF 32

typedef float v4f __attribute__((ext_vector_type(4)));
typedef short v8s __attribute__((ext_vector_type(8)));

static __device__ __forceinline__ ushort f2bf(float f) {
    union { float f; uint u; } v; v.f = f;
    uint u = v.u;
    uint r = (u + 0x7fffu + ((u >> 16) & 1u)) >> 16;   // round-nearest-even
    return (ushort)r;
}

#define MFMA16(a, b, c) __builtin_amdgcn_mfma_f32_16x16x32_bf16(a, b, c, 0, 0, 0)

// ---------------------------------------------------------------------------
// Kernel 1: transpose + cast weights to bf16.  WhT[c][k], WfT[cf][k], WgT[cf][k]
// ---------------------------------------------------------------------------
__global__ void prep_weights(const float* __restrict__ kf, const float* __restrict__ kg,
                             const float* __restrict__ kh,
                             ushort* __restrict__ wfT, ushort* __restrict__ wgT,
                             ushort* __restrict__ whT) {
    int t = threadIdx.x;  // 256 threads, 1 block
    for (int i = t; i < CH * CH; i += 256) {
        int c = i >> 8, k = i & 255;
        whT[i] = f2bf(kh[k * CH + c]);
    }
    for (int i = t; i < CF * CH; i += 256) {
        int cf = i >> 8, k = i & 255;
        wfT[i] = f2bf(kf[k * CF + cf]);
        wgT[i] = f2bf(kg[k * CF + cf]);
    }
}

// ---------------------------------------------------------------------------
// Kernel 2: f = x*Wf + bf, g = x*Wg + bg   (row-major [32768][32] bf16)
// block = 256 thr = 4 waves; each wave: 16 rows of n; grid 512
// ---------------------------------------------------------------------------
__global__ __launch_bounds__(256) void proj_fg(
    const float* __restrict__ x, const ushort* __restrict__ wfT,
    const ushort* __restrict__ wgT, const float* __restrict__ bf,
    const float* __restrict__ bg, ushort* __restrict__ fo, ushort* __restrict__ go) {
    int lane = threadIdx.x & 63, w = threadIdx.x >> 6;
    int row = lane & 15, g4 = lane >> 4;
    int n0 = blockIdx.x * 64 + w * 16;

    v4f accF0 = {}, accF1 = {}, accG0 = {}, accG1 = {};
    for (int kk = 0; kk < CH; kk += 32) {
        const float* xp = x + (size_t)(n0 + row) * CH + kk + g4 * 8;
        float4 x0 = ((const float4*)xp)[0];
        float4 x1 = ((const float4*)xp)[1];
        v8s a;
        a[0] = (short)f2bf(x0.x); a[1] = (short)f2bf(x0.y);
        a[2] = (short)f2bf(x0.z); a[3] = (short)f2bf(x0.w);
        a[4] = (short)f2bf(x1.x); a[5] = (short)f2bf(x1.y);
        a[6] = (short)f2bf(x1.z); a[7] = (short)f2bf(x1.w);
        v8s bF0 = *(const v8s*)(wfT + (size_t)row * CH + kk + g4 * 8);
        v8s bF1 = *(const v8s*)(wfT + (size_t)(16 + row) * CH + kk + g4 * 8);
        v8s bG0 = *(const v8s*)(wgT + (size_t)row * CH + kk + g4 * 8);
        v8s bG1 = *(const v8s*)(wgT + (size_t)(16 + row) * CH + kk + g4 * 8);
        accF0 = MFMA16(a, bF0, accF0);
        accF1 = MFMA16(a, bF1, accF1);
        accG0 = MFMA16(a, bG0, accG0);
        accG1 = MFMA16(a, bG1, accG1);
    }
#pragma unroll
    for (int r = 0; r < 4; ++r) {
        int n = n0 + g4 * 4 + r;
        fo[(size_t)n * CF + row]      = f2bf(accF0[r] + bf[row]);
        fo[(size_t)n * CF + 16 + row] = f2bf(accF1[r] + bf[16 + row]);
        go[(size_t)n * CF + row]      = f2bf(accG0[r] + bg[row]);
        go[(size_t)n * CF + 16 + row] = f2bf(accG1[r] + bg[16 + row]);
    }
}

// ---------------------------------------------------------------------------
// Kernel 3: hT[b][c][n] = (x*Wh + bh)^T  (bf16).  Computed as Wh^T * x^T.
// grid (512 n-tiles, 4 c-tiles); block 256 = 4 waves; wave: 16 c x 64 n
// ---------------------------------------------------------------------------
__global__ __launch_bounds__(256) void proj_hT(
    const float* __restrict__ x, const ushort* __restrict__ whT,
    const float* __restrict__ bh, ushort* __restrict__ hT) {
    int lane = threadIdx.x & 63, w = threadIdx.x >> 6;
    int row = lane & 15, g4 = lane >> 4;
    int n0 = blockIdx.x * 64;
    int c0 = blockIdx.y * 64 + w * 16;

    v4f acc[4] = {};
    for (int kk = 0; kk < CH; kk += 32) {
        v8s a = *(const v8s*)(whT + (size_t)(c0 + row) * CH + kk + g4 * 8);
#pragma unroll
        for (int nt = 0; nt < 4; ++nt) {
            const float* xp = x + (size_t)(n0 + nt * 16 + row) * CH + kk + g4 * 8;
            float4 x0 = ((const float4*)xp)[0];
            float4 x1 = ((const float4*)xp)[1];
            v8s b;
            b[0] = (short)f2bf(x0.x); b[1] = (short)f2bf(x0.y);
            b[2] = (short)f2bf(x0.z); b[3] = (short)f2bf(x0.w);
            b[4] = (short)f2bf(x1.x); b[5] = (short)f2bf(x1.y);
            b[6] = (short)f2bf(x1.z); b[7] = (short)f2bf(x1.w);
            acc[nt] = MFMA16(a, b, acc[nt]);
        }
    }
#pragma unroll
    for (int nt = 0; nt < 4; ++nt) {
        int n = n0 + nt * 16 + row;
        int b = n >> 12, nn = n & (NTOK - 1);
#pragma unroll
        for (int r = 0; r < 4; ++r) {
            int c = c0 + g4 * 4 + r;
            hT[(size_t)b * CH * NTOK + (size_t)c * NTOK + nn] = f2bf(acc[nt][r] + bh[c]);
        }
    }
}

// ---------------------------------------------------------------------------
// Kernel 4: flash attention.  Per wave: 16 q rows; block = 4 waves = 64 q.
// grid 512: bid&7 = batch (XCD-local L2 reuse of hT/f), bid>>3 = q-block.
// S^T = K*Q^T  (lane holds S^T[key = g4*4+r][q = lane&15]); online softmax;
// P transposed through a tiny per-wave LDS tile; O += P*V with V = hT rows.
// ---------------------------------------------------------------------------
__global__ __launch_bounds__(256) void flash_attn(
    const ushort* __restrict__ fbuf, const ushort* __restrict__ gbuf,
    const ushort* __restrict__ hT, const float* __restrict__ x,
    const float* __restrict__ gamma, float* __restrict__ out) {
    __shared__ __align__(16) ushort lds_p[4][16][88];   // [wave][q][key(64, pad 88)]
    int lane = threadIdx.x & 63, w = threadIdx.x >> 6;
    int row = lane & 15, g4 = lane >> 4;
    int bid = blockIdx.x;
    int batch = bid & 7;
    int q0 = (bid >> 3) * 64 + w * 16;

    const ushort* fB = fbuf + (size_t)batch * NTOK * CF;
    const ushort* gB = gbuf + (size_t)batch * NTOK * CF;
    const ushort* hB = hT + (size_t)batch * CH * NTOK;

    // Q^T B-fragment: g[q0+row][g4*8 .. +7]  (lives across the whole loop)
    v8s bq = *(const v8s*)(gB + (size_t)(q0 + row) * CF + g4 * 8);

    float m = -1e30f, lsum = 0.f;
    v4f acc[16] = {};   // O tile: 16 q x 256 c
    const v4f vzero = {};

    for (int kb = 0; kb < NTOK; kb += 64) {
        // ---- S^T tiles: 4 x (16 key x 16 q) ----
        v4f s[4];
#pragma unroll
        for (int t = 0; t < 4; ++t) {
            v8s ak = *(const v8s*)(fB + (size_t)(kb + t * 16 + row) * CF + g4 * 8);
            s[t] = MFMA16(ak, bq, vzero);
        }
        // ---- online softmax (state per q = lane&15) ----
        float tmax = -1e30f;
#pragma unroll
        for (int t = 0; t < 4; ++t)
#pragma unroll
            for (int r = 0; r < 4; ++r) tmax = fmaxf(tmax, s[t][r]);
        tmax = fmaxf(tmax, __shfl_xor(tmax, 16));
        tmax = fmaxf(tmax, __shfl_xor(tmax, 32));
        float mn = fmaxf(m, tmax);
        float scale = __builtin_amdgcn_exp2f((m - mn) * 1.44269504f);
        m = mn;
        float psum = 0.f;
        uint pk[4][2];
#pragma unroll
        for (int t = 0; t < 4; ++t) {
            float p0 = __builtin_amdgcn_exp2f((s[t][0] - m) * 1.44269504f);
            float p1 = __builtin_amdgcn_exp2f((s[t][1] - m) * 1.44269504f);
            float p2 = __builtin_amdgcn_exp2f((s[t][2] - m) * 1.44269504f);
            float p3 = __builtin_amdgcn_exp2f((s[t][3] - m) * 1.44269504f);
            psum += (p0 + p1) + (p2 + p3);
            pk[t][0] = (uint)f2bf(p0) | ((uint)f2bf(p1) << 16);
            pk[t][1] = (uint)f2bf(p2) | ((uint)f2bf(p3) << 16);
        }
        psum += __shfl_xor(psum, 16);
        psum += __shfl_xor(psum, 32);
        lsum = lsum * scale + psum;
        // ---- rescale O (O rows are q = g4*4+r -> fetch that q's scale) ----
        float scr[4];
#pragma unroll
        for (int r = 0; r < 4; ++r) scr[r] = __shfl(scale, g4 * 4 + r, 16);
#pragma unroll
        for (int ct = 0; ct < 16; ++ct)
#pragma unroll
            for (int r = 0; r < 4; ++r) acc[ct][r] *= scr[r];
        // ---- P -> LDS (transpose to [q][key]) ----
#pragma unroll
        for (int t = 0; t < 4; ++t) {
            uint* dst = (uint*)&lds_p[w][row][t * 16 + g4 * 4];
            dst[0] = pk[t][0];
            dst[1] = pk[t][1];
        }
        __builtin_amdgcn_sched_barrier(0);
        asm volatile("s_waitcnt lgkmcnt(0)" ::: "memory");
        __builtin_amdgcn_sched_barrier(0);
        v8s pa0 = *(const v8s*)&lds_p[w][row][g4 * 8];        // keys 0..31 frag
        v8s pa1 = *(const v8s*)&lds_p[w][row][32 + g4 * 8];   // keys 32..63 frag
        // ---- O += P * V  (V rows from hT: contiguous along keys) ----
#pragma unroll
        for (int ct = 0; ct < 16; ++ct) {
            const ushort* hp = hB + (size_t)(ct * 16 + row) * NTOK + kb;
            v8s bv0 = *(const v8s*)(hp + g4 * 8);
            v8s bv1 = *(const v8s*)(hp + 32 + g4 * 8);
            acc[ct] = MFMA16(pa0, bv0, acc[ct]);
            acc[ct] = MFMA16(pa1, bv1, acc[ct]);
        }
    }
    // ---- epilogue: out = gamma * O/lsum + x ----
    float gm = gamma[0];
    float li[4];
#pragma unroll
    for (int r = 0; r < 4; ++r) li[r] = 1.f / __shfl(lsum, g4 * 4 + r, 16);
#pragma unroll
    for (int ct = 0; ct < 16; ++ct) {
        int c = ct * 16 + row;
#pragma unroll
        for (int r = 0; r < 4; ++r) {
            size_t idx = ((size_t)batch * NTOK + q0 + g4 * 4 + r) * CH + c;
            out[idx] = gm * (acc[ct][r] * li[r]) + x[idx];
        }
    }
}

// ---------------------------------------------------------------------------
extern "C" void kernel_launch(void* const* d_in, const int* in_sizes, int n_in,
                              void* d_out, int out_size, void* d_ws, size_t ws_size,
                              hipStream_t stream) {
    const float* x  = (const float*)d_in[0];
    const float* kf = (const float*)d_in[1];
    const float* kg = (const float*)d_in[2];
    const float* kh = (const float*)d_in[3];
    const float* bf = (const float*)d_in[4];
    const float* bg = (const float*)d_in[5];
    const float* bh = (const float*)d_in[6];
    const float* gm = (const float*)d_in[7];
    float* out = (float*)d_out;

    char* ws = (char*)d_ws;
    ushort* wfT = (ushort*)(ws);                       //  16 KB
    ushort* wgT = (ushort*)(ws + 16384);               //  16 KB
    ushort* whT = (ushort*)(ws + 32768);               // 128 KB
    ushort* fo  = (ushort*)(ws + 163840);              //   2 MB
    ushort* go  = (ushort*)(ws + 163840 + 2097152);    //   2 MB
    ushort* hT  = (ushort*)(ws + 163840 + 4194304);    //  16 MB
    // total ws use: ~21.1 MB

    hipLaunchKernelGGL(prep_weights, dim3(1), dim3(256), 0, stream, kf, kg, kh, wfT, wgT, whT);
    hipLaunchKernelGGL(proj_fg, dim3(512), dim3(256), 0, stream, x, wfT, wgT, bf, bg, fo, go);
    hipLaunchKernelGGL(proj_hT, dim3(512, 4), dim3(256), 0, stream, x, whT, bh, hT);
    hipLaunchKernelGGL(flash_attn, dim3(512), dim3(256), 0, stream, fo, go, hT, x, gm, out);
}

// Round 3
// 240.291 us; speedup vs baseline: 2.6021x; 2.6021x over previous
//
#include <hip/hip_runtime.h>
#include <hip/hip_bf16.h>

#define BATCH 8
#define NTOK 4096      // H*W per batch
#define CH 256
#define CF 32
#define KVBLK 64
#define NITER (NTOK / KVBLK)

typedef float v4f __attribute__((ext_vector_type(4)));
typedef short v8s __attribute__((ext_vector_type(8)));

static __device__ __forceinline__ ushort f2bf(float f) {
    union { float f; uint u; } v; v.f = f;
    uint u = v.u;
    uint r = (u + 0x7fffu + ((u >> 16) & 1u)) >> 16;   // round-nearest-even
    return (ushort)r;
}

static __device__ __forceinline__ void gload16(const void* g, void* l) {
    __builtin_amdgcn_global_load_lds(
        (const __attribute__((address_space(1))) unsigned int*)g,
        (__attribute__((address_space(3))) unsigned int*)l, 16, 0, 0);
}

#define MFMA16(a, b, c) __builtin_amdgcn_mfma_f32_16x16x32_bf16(a, b, c, 0, 0, 0)

// ---------------------------------------------------------------------------
// Kernel 1: transpose + cast weights to bf16.  WhT[c][k], WfT[cf][k], WgT[cf][k]
// ---------------------------------------------------------------------------
__global__ void prep_weights(const float* __restrict__ kf, const float* __restrict__ kg,
                             const float* __restrict__ kh,
                             ushort* __restrict__ wfT, ushort* __restrict__ wgT,
                             ushort* __restrict__ whT) {
    int t = threadIdx.x;  // 256 threads, 1 block
    for (int i = t; i < CH * CH; i += 256) {
        int c = i >> 8, k = i & 255;
        whT[i] = f2bf(kh[k * CH + c]);
    }
    for (int i = t; i < CF * CH; i += 256) {
        int cf = i >> 8, k = i & 255;
        wfT[i] = f2bf(kf[k * CF + cf]);
        wgT[i] = f2bf(kg[k * CF + cf]);
    }
}

// ---------------------------------------------------------------------------
// Kernel 2: f = x*Wf + bf, g = x*Wg + bg   (row-major [32768][32] bf16)
// ---------------------------------------------------------------------------
__global__ __launch_bounds__(256) void proj_fg(
    const float* __restrict__ x, const ushort* __restrict__ wfT,
    const ushort* __restrict__ wgT, const float* __restrict__ bf,
    const float* __restrict__ bg, ushort* __restrict__ fo, ushort* __restrict__ go) {
    int lane = threadIdx.x & 63, w = threadIdx.x >> 6;
    int row = lane & 15, g4 = lane >> 4;
    int n0 = blockIdx.x * 64 + w * 16;

    v4f accF0 = {}, accF1 = {}, accG0 = {}, accG1 = {};
    for (int kk = 0; kk < CH; kk += 32) {
        const float* xp = x + (size_t)(n0 + row) * CH + kk + g4 * 8;
        float4 x0 = ((const float4*)xp)[0];
        float4 x1 = ((const float4*)xp)[1];
        v8s a;
        a[0] = (short)f2bf(x0.x); a[1] = (short)f2bf(x0.y);
        a[2] = (short)f2bf(x0.z); a[3] = (short)f2bf(x0.w);
        a[4] = (short)f2bf(x1.x); a[5] = (short)f2bf(x1.y);
        a[6] = (short)f2bf(x1.z); a[7] = (short)f2bf(x1.w);
        v8s bF0 = *(const v8s*)(wfT + (size_t)row * CH + kk + g4 * 8);
        v8s bF1 = *(const v8s*)(wfT + (size_t)(16 + row) * CH + kk + g4 * 8);
        v8s bG0 = *(const v8s*)(wgT + (size_t)row * CH + kk + g4 * 8);
        v8s bG1 = *(const v8s*)(wgT + (size_t)(16 + row) * CH + kk + g4 * 8);
        accF0 = MFMA16(a, bF0, accF0);
        accF1 = MFMA16(a, bF1, accF1);
        accG0 = MFMA16(a, bG0, accG0);
        accG1 = MFMA16(a, bG1, accG1);
    }
#pragma unroll
    for (int r = 0; r < 4; ++r) {
        int n = n0 + g4 * 4 + r;
        fo[(size_t)n * CF + row]      = f2bf(accF0[r] + bf[row]);
        fo[(size_t)n * CF + 16 + row] = f2bf(accF1[r] + bf[16 + row]);
        go[(size_t)n * CF + row]      = f2bf(accG0[r] + bg[row]);
        go[(size_t)n * CF + 16 + row] = f2bf(accG1[r] + bg[16 + row]);
    }
}

// ---------------------------------------------------------------------------
// Kernel 3: hT[b][c][n] = (x*Wh + bh)^T  (bf16)
// ---------------------------------------------------------------------------
__global__ __launch_bounds__(256) void proj_hT(
    const float* __restrict__ x, const ushort* __restrict__ whT,
    const float* __restrict__ bh, ushort* __restrict__ hT) {
    int lane = threadIdx.x & 63, w = threadIdx.x >> 6;
    int row = lane & 15, g4 = lane >> 4;
    int n0 = blockIdx.x * 64;
    int c0 = blockIdx.y * 64 + w * 16;

    v4f acc[4] = {};
    for (int kk = 0; kk < CH; kk += 32) {
        v8s a = *(const v8s*)(whT + (size_t)(c0 + row) * CH + kk + g4 * 8);
#pragma unroll
        for (int nt = 0; nt < 4; ++nt) {
            const float* xp = x + (size_t)(n0 + nt * 16 + row) * CH + kk + g4 * 8;
            float4 x0 = ((const float4*)xp)[0];
            float4 x1 = ((const float4*)xp)[1];
            v8s b;
            b[0] = (short)f2bf(x0.x); b[1] = (short)f2bf(x0.y);
            b[2] = (short)f2bf(x0.z); b[3] = (short)f2bf(x0.w);
            b[4] = (short)f2bf(x1.x); b[5] = (short)f2bf(x1.y);
            b[6] = (short)f2bf(x1.z); b[7] = (short)f2bf(x1.w);
            acc[nt] = MFMA16(a, b, acc[nt]);
        }
    }
#pragma unroll
    for (int nt = 0; nt < 4; ++nt) {
        int n = n0 + nt * 16 + row;
        int b = n >> 12, nn = n & (NTOK - 1);
#pragma unroll
        for (int r = 0; r < 4; ++r) {
            int c = c0 + g4 * 4 + r;
            hT[(size_t)b * CH * NTOK + (size_t)c * NTOK + nn] = f2bf(acc[nt][r] + bh[c]);
        }
    }
}

// ---------------------------------------------------------------------------
// Kernel 4: flash attention, LDS-staged + double-buffered.
// 512 thr = 8 waves x 16 q = 128 q per block; grid 256 (1 block/CU).
// bid&7 = batch (XCD L2 locality).  Shared tiles per kb:
//   f tile  [64 key][32 cf]  4 KB (chunk16B ^ (key>>1)&3 swizzle)
//   V tile  [256 c][64 key] 32 KB (chunk16B ^ c&7 swizzle)
// staged with global_load_lds(16B) from pre-swizzled global addresses.
// ---------------------------------------------------------------------------
__global__ __launch_bounds__(512, 2) void flash_attn(
    const ushort* __restrict__ fbuf, const ushort* __restrict__ gbuf,
    const ushort* __restrict__ hT, const float* __restrict__ x,
    const float* __restrict__ gamma, float* __restrict__ out) {
    __shared__ __align__(16) ushort lds_f[2][2048];    //  8 KB total
    __shared__ __align__(16) ushort lds_v[2][16384];   // 64 KB total
    __shared__ __align__(16) ushort lds_p[8][16][88];  // 22.5 KB

    int tid = threadIdx.x;
    int lane = tid & 63, w = tid >> 6;
    int row = lane & 15, g4 = lane >> 4;
    int batch = blockIdx.x & 7;
    int q0 = (blockIdx.x >> 3) * 128 + w * 16;

    const ushort* fB = fbuf + (size_t)batch * NTOK * CF;
    const ushort* gB = gbuf + (size_t)batch * NTOK * CF;
    const ushort* hB = hT + (size_t)batch * CH * NTOK;

#define STAGE(buf, kb) do {                                                     \
        _Pragma("unroll")                                                       \
        for (int i_ = 0; i_ < 4; ++i_) {                                        \
            int g_ = i_ * 512 + tid;                                            \
            int c_ = g_ >> 3, ch_ = g_ & 7;                                     \
            const ushort* s_ = hB + (size_t)c_ * NTOK + (kb) + ((ch_ ^ (c_ & 7)) << 3); \
            gload16(s_, (char*)&lds_v[buf][0] + g_ * 16);                       \
        }                                                                       \
        if (tid < 256) {                                                        \
            int k_ = tid >> 2, ch_ = tid & 3;                                   \
            const ushort* s_ = fB + (size_t)((kb) + k_) * CF + ((ch_ ^ ((k_ >> 1) & 3)) << 3); \
            gload16(s_, (char*)&lds_f[buf][0] + tid * 16);                      \
        }                                                                       \
    } while (0)

    // Q^T B-fragment, lives across the whole loop
    v8s bq = *(const v8s*)(gB + (size_t)(q0 + row) * CF + g4 * 8);

    float m = -1e30f, lsum = 0.f;
    v4f acc[16] = {};   // O tile: 16 q x 256 c
    const v4f vzero = {};

    STAGE(0, 0);
    __syncthreads();

    for (int t = 0; t < NITER; ++t) {
        int cur = t & 1;
        if (t + 1 < NITER) STAGE(cur ^ 1, (t + 1) * KVBLK);

        const char* fb = (const char*)&lds_f[cur][0];
        const char* vb = (const char*)&lds_v[cur][0];

        // ---- S^T tiles: 4 x (16 key x 16 q) ----
        v4f s[4];
#pragma unroll
        for (int tt = 0; tt < 4; ++tt) {
            int key = tt * 16 + row;
            v8s ak = *(const v8s*)(fb + key * 64 + ((g4 ^ ((key >> 1) & 3)) << 4));
            s[tt] = MFMA16(ak, bq, vzero);
        }
        // ---- online softmax (state per q = lane&15) ----
        float tmax = -1e30f;
#pragma unroll
        for (int tt = 0; tt < 4; ++tt)
#pragma unroll
            for (int r = 0; r < 4; ++r) tmax = fmaxf(tmax, s[tt][r]);
        tmax = fmaxf(tmax, __shfl_xor(tmax, 16));
        tmax = fmaxf(tmax, __shfl_xor(tmax, 32));
        float mn = fmaxf(m, tmax);
        float scale = __builtin_amdgcn_exp2f((m - mn) * 1.44269504f);
        m = mn;
        float psum = 0.f;
        uint pk[4][2];
#pragma unroll
        for (int tt = 0; tt < 4; ++tt) {
            float p0 = __builtin_amdgcn_exp2f((s[tt][0] - m) * 1.44269504f);
            float p1 = __builtin_amdgcn_exp2f((s[tt][1] - m) * 1.44269504f);
            float p2 = __builtin_amdgcn_exp2f((s[tt][2] - m) * 1.44269504f);
            float p3 = __builtin_amdgcn_exp2f((s[tt][3] - m) * 1.44269504f);
            psum += (p0 + p1) + (p2 + p3);
            pk[tt][0] = (uint)f2bf(p0) | ((uint)f2bf(p1) << 16);
            pk[tt][1] = (uint)f2bf(p2) | ((uint)f2bf(p3) << 16);
        }
        psum += __shfl_xor(psum, 16);
        psum += __shfl_xor(psum, 32);
        lsum = lsum * scale + psum;
        // ---- rescale O ----
        float scr[4];
#pragma unroll
        for (int r = 0; r < 4; ++r) scr[r] = __shfl(scale, g4 * 4 + r, 16);
#pragma unroll
        for (int ct = 0; ct < 16; ++ct)
#pragma unroll
            for (int r = 0; r < 4; ++r) acc[ct][r] *= scr[r];
        // ---- P -> per-wave LDS tile (transpose to [q][key]) ----
#pragma unroll
        for (int tt = 0; tt < 4; ++tt) {
            uint* dst = (uint*)&lds_p[w][row][tt * 16 + g4 * 4];
            dst[0] = pk[tt][0];
            dst[1] = pk[tt][1];
        }
        __builtin_amdgcn_sched_barrier(0);
        asm volatile("s_waitcnt lgkmcnt(0)" ::: "memory");
        __builtin_amdgcn_sched_barrier(0);
        v8s pa0 = *(const v8s*)&lds_p[w][row][g4 * 8];        // keys 0..31
        v8s pa1 = *(const v8s*)&lds_p[w][row][32 + g4 * 8];   // keys 32..63
        // ---- O += P * V  (V B-frags from swizzled LDS) ----
#pragma unroll
        for (int ct = 0; ct < 16; ++ct) {
            int c = ct * 16 + row;
            v8s bv0 = *(const v8s*)(vb + c * 128 + ((g4 ^ (c & 7)) << 4));
            v8s bv1 = *(const v8s*)(vb + c * 128 + (((4 + g4) ^ (c & 7)) << 4));
            acc[ct] = MFMA16(pa0, bv0, acc[ct]);
            acc[ct] = MFMA16(pa1, bv1, acc[ct]);
        }
        __syncthreads();
    }
#undef STAGE

    // ---- epilogue: out = gamma * O/lsum + x ----
    float gm = gamma[0];
    float li[4];
#pragma unroll
    for (int r = 0; r < 4; ++r) li[r] = 1.f / __shfl(lsum, g4 * 4 + r, 16);
#pragma unroll
    for (int ct = 0; ct < 16; ++ct) {
        int c = ct * 16 + row;
#pragma unroll
        for (int r = 0; r < 4; ++r) {
            size_t idx = ((size_t)batch * NTOK + q0 + g4 * 4 + r) * CH + c;
            out[idx] = gm * (acc[ct][r] * li[r]) + x[idx];
        }
    }
}

// ---------------------------------------------------------------------------
extern "C" void kernel_launch(void* const* d_in, const int* in_sizes, int n_in,
                              void* d_out, int out_size, void* d_ws, size_t ws_size,
                              hipStream_t stream) {
    const float* x  = (const float*)d_in[0];
    const float* kf = (const float*)d_in[1];
    const float* kg = (const float*)d_in[2];
    const float* kh = (const float*)d_in[3];
    const float* bf = (const float*)d_in[4];
    const float* bg = (const float*)d_in[5];
    const float* bh = (const float*)d_in[6];
    const float* gm = (const float*)d_in[7];
    float* out = (float*)d_out;

    char* ws = (char*)d_ws;
    ushort* wfT = (ushort*)(ws);                       //  16 KB
    ushort* wgT = (ushort*)(ws + 16384);               //  16 KB
    ushort* whT = (ushort*)(ws + 32768);               // 128 KB
    ushort* fo  = (ushort*)(ws + 163840);              //   2 MB
    ushort* go  = (ushort*)(ws + 163840 + 2097152);    //   2 MB
    ushort* hT  = (ushort*)(ws + 163840 + 4194304);    //  16 MB

    hipLaunchKernelGGL(prep_weights, dim3(1), dim3(256), 0, stream, kf, kg, kh, wfT, wgT, whT);
    hipLaunchKernelGGL(proj_fg, dim3(512), dim3(256), 0, stream, x, wfT, wgT, bf, bg, fo, go);
    hipLaunchKernelGGL(proj_hT, dim3(512, 4), dim3(256), 0, stream, x, whT, bh, hT);
    hipLaunchKernelGGL(flash_attn, dim3(256), dim3(512), 0, stream, fo, go, hT, x, gm, out);
}

// Round 4
// 207.406 us; speedup vs baseline: 3.0147x; 1.1586x over previous
//
#include <hip/hip_runtime.h>
#include <hip/hip_bf16.h>

#define BATCH 8
#define NTOK 4096      // H*W per batch
#define CH 256
#define CF 32
#define KVBLK 64
#define NITER (NTOK / KVBLK)

typedef float v4f __attribute__((ext_vector_type(4)));
typedef short v8s __attribute__((ext_vector_type(8)));

static __device__ __forceinline__ ushort f2bf(float f) {
    union { float f; uint u; } v; v.f = f;
    uint u = v.u;
    uint r = (u + 0x7fffu + ((u >> 16) & 1u)) >> 16;   // round-nearest-even
    return (ushort)r;
}

static __device__ __forceinline__ void gload16(const void* g, void* l) {
    __builtin_amdgcn_global_load_lds(
        (const __attribute__((address_space(1))) unsigned int*)g,
        (__attribute__((address_space(3))) unsigned int*)l, 16, 0, 0);
}

#define MFMA16(a, b, c) __builtin_amdgcn_mfma_f32_16x16x32_bf16(a, b, c, 0, 0, 0)

// ---------------------------------------------------------------------------
// Kernel 1: transpose + cast weights to bf16 (parallel, coalesced reads).
// grid 256 x 256 thr: whT[c][k] = kh[k][c]; wfT/wgT likewise.
// ---------------------------------------------------------------------------
__global__ __launch_bounds__(256) void prep_weights(
    const float* __restrict__ kf, const float* __restrict__ kg,
    const float* __restrict__ kh,
    ushort* __restrict__ wfT, ushort* __restrict__ wgT, ushort* __restrict__ whT) {
    int i = blockIdx.x * 256 + threadIdx.x;   // 65536 threads total
    {   // Wh: 256x256
        int k = i >> 8, c = i & 255;
        whT[c * CH + k] = f2bf(kh[i]);
    }
    if (i < CH * CF) {  // Wf/Wg: 256x32
        int k = i >> 5, cf = i & 31;
        wfT[cf * CH + k] = f2bf(kf[i]);
        wgT[cf * CH + k] = f2bf(kg[i]);
    }
}

// ---------------------------------------------------------------------------
// Kernel 2: f = x*Wf + bf, g = x*Wg + bg   (row-major [32768][32] bf16)
// ---------------------------------------------------------------------------
__global__ __launch_bounds__(256) void proj_fg(
    const float* __restrict__ x, const ushort* __restrict__ wfT,
    const ushort* __restrict__ wgT, const float* __restrict__ bf,
    const float* __restrict__ bg, ushort* __restrict__ fo, ushort* __restrict__ go) {
    int lane = threadIdx.x & 63, w = threadIdx.x >> 6;
    int row = lane & 15, g4 = lane >> 4;
    int n0 = blockIdx.x * 64 + w * 16;

    v4f accF0 = {}, accF1 = {}, accG0 = {}, accG1 = {};
    for (int kk = 0; kk < CH; kk += 32) {
        const float* xp = x + (size_t)(n0 + row) * CH + kk + g4 * 8;
        float4 x0 = ((const float4*)xp)[0];
        float4 x1 = ((const float4*)xp)[1];
        v8s a;
        a[0] = (short)f2bf(x0.x); a[1] = (short)f2bf(x0.y);
        a[2] = (short)f2bf(x0.z); a[3] = (short)f2bf(x0.w);
        a[4] = (short)f2bf(x1.x); a[5] = (short)f2bf(x1.y);
        a[6] = (short)f2bf(x1.z); a[7] = (short)f2bf(x1.w);
        v8s bF0 = *(const v8s*)(wfT + (size_t)row * CH + kk + g4 * 8);
        v8s bF1 = *(const v8s*)(wfT + (size_t)(16 + row) * CH + kk + g4 * 8);
        v8s bG0 = *(const v8s*)(wgT + (size_t)row * CH + kk + g4 * 8);
        v8s bG1 = *(const v8s*)(wgT + (size_t)(16 + row) * CH + kk + g4 * 8);
        accF0 = MFMA16(a, bF0, accF0);
        accF1 = MFMA16(a, bF1, accF1);
        accG0 = MFMA16(a, bG0, accG0);
        accG1 = MFMA16(a, bG1, accG1);
    }
#pragma unroll
    for (int r = 0; r < 4; ++r) {
        int n = n0 + g4 * 4 + r;
        fo[(size_t)n * CF + row]      = f2bf(accF0[r] + bf[row]);
        fo[(size_t)n * CF + 16 + row] = f2bf(accF1[r] + bf[16 + row]);
        go[(size_t)n * CF + row]      = f2bf(accG0[r] + bg[row]);
        go[(size_t)n * CF + 16 + row] = f2bf(accG1[r] + bg[16 + row]);
    }
}

// ---------------------------------------------------------------------------
// Kernel 3: hT[b][c][n] = (x*Wh + bh)^T  (bf16)
// ---------------------------------------------------------------------------
__global__ __launch_bounds__(256) void proj_hT(
    const float* __restrict__ x, const ushort* __restrict__ whT,
    const float* __restrict__ bh, ushort* __restrict__ hT) {
    int lane = threadIdx.x & 63, w = threadIdx.x >> 6;
    int row = lane & 15, g4 = lane >> 4;
    int n0 = blockIdx.x * 64;
    int c0 = blockIdx.y * 64 + w * 16;

    v4f acc[4] = {};
    for (int kk = 0; kk < CH; kk += 32) {
        v8s a = *(const v8s*)(whT + (size_t)(c0 + row) * CH + kk + g4 * 8);
#pragma unroll
        for (int nt = 0; nt < 4; ++nt) {
            const float* xp = x + (size_t)(n0 + nt * 16 + row) * CH + kk + g4 * 8;
            float4 x0 = ((const float4*)xp)[0];
            float4 x1 = ((const float4*)xp)[1];
            v8s b;
            b[0] = (short)f2bf(x0.x); b[1] = (short)f2bf(x0.y);
            b[2] = (short)f2bf(x0.z); b[3] = (short)f2bf(x0.w);
            b[4] = (short)f2bf(x1.x); b[5] = (short)f2bf(x1.y);
            b[6] = (short)f2bf(x1.z); b[7] = (short)f2bf(x1.w);
            acc[nt] = MFMA16(a, b, acc[nt]);
        }
    }
#pragma unroll
    for (int nt = 0; nt < 4; ++nt) {
        int n = n0 + nt * 16 + row;
        int b = n >> 12, nn = n & (NTOK - 1);
#pragma unroll
        for (int r = 0; r < 4; ++r) {
            int c = c0 + g4 * 4 + r;
            hT[(size_t)b * CH * NTOK + (size_t)c * NTOK + nn] = f2bf(acc[nt][r] + bh[c]);
        }
    }
}

// ---------------------------------------------------------------------------
// Kernel 4: flash attention, LDS-staged + double-buffered + defer-max.
// 512 thr = 8 waves x 16 q = 128 q per block; grid 256 (1 block/CU).
// ---------------------------------------------------------------------------
__global__ __launch_bounds__(512, 2) void flash_attn(
    const ushort* __restrict__ fbuf, const ushort* __restrict__ gbuf,
    const ushort* __restrict__ hT, const float* __restrict__ x,
    const float* __restrict__ gamma, float* __restrict__ out) {
    __shared__ __align__(16) ushort lds_f[2][2048];    //  8 KB total
    __shared__ __align__(16) ushort lds_v[2][16384];   // 64 KB total
    __shared__ __align__(16) ushort lds_p[8][16][88];  // 22.5 KB

    int tid = threadIdx.x;
    int lane = tid & 63, w = tid >> 6;
    int row = lane & 15, g4 = lane >> 4;
    int batch = blockIdx.x & 7;
    int q0 = (blockIdx.x >> 3) * 128 + w * 16;

    const ushort* fB = fbuf + (size_t)batch * NTOK * CF;
    const ushort* gB = gbuf + (size_t)batch * NTOK * CF;
    const ushort* hB = hT + (size_t)batch * CH * NTOK;

#define STAGE(buf, kb) do {                                                     \
        _Pragma("unroll")                                                       \
        for (int i_ = 0; i_ < 4; ++i_) {                                        \
            int g_ = i_ * 512 + tid;                                            \
            int c_ = g_ >> 3, ch_ = g_ & 7;                                     \
            const ushort* s_ = hB + (size_t)c_ * NTOK + (kb) + ((ch_ ^ (c_ & 7)) << 3); \
            gload16(s_, (char*)&lds_v[buf][0] + g_ * 16);                       \
        }                                                                       \
        if (tid < 256) {                                                        \
            int k_ = tid >> 2, ch_ = tid & 3;                                   \
            const ushort* s_ = fB + (size_t)((kb) + k_) * CF + ((ch_ ^ ((k_ >> 1) & 3)) << 3); \
            gload16(s_, (char*)&lds_f[buf][0] + tid * 16);                      \
        }                                                                       \
    } while (0)

    // Q^T B-fragment, lives across the whole loop
    v8s bq = *(const v8s*)(gB + (size_t)(q0 + row) * CF + g4 * 8);

    float m = -1e30f, lsum = 0.f;
    v4f acc[16] = {};   // O tile: 16 q x 256 c
    const v4f vzero = {};

    STAGE(0, 0);
    __syncthreads();

    for (int t = 0; t < NITER; ++t) {
        int cur = t & 1;
        if (t + 1 < NITER) STAGE(cur ^ 1, (t + 1) * KVBLK);

        const char* fb = (const char*)&lds_f[cur][0];
        const char* vb = (const char*)&lds_v[cur][0];

        // ---- S^T tiles: 4 x (16 key x 16 q) ----
        v4f s[4];
#pragma unroll
        for (int tt = 0; tt < 4; ++tt) {
            int key = tt * 16 + row;
            v8s ak = *(const v8s*)(fb + key * 64 + ((g4 ^ ((key >> 1) & 3)) << 4));
            s[tt] = MFMA16(ak, bq, vzero);
        }
        // ---- online softmax with defer-max (state per q = lane&15) ----
        float tmax = -1e30f;
#pragma unroll
        for (int tt = 0; tt < 4; ++tt)
#pragma unroll
            for (int r = 0; r < 4; ++r) tmax = fmaxf(tmax, s[tt][r]);
        tmax = fmaxf(tmax, __shfl_xor(tmax, 16));
        tmax = fmaxf(tmax, __shfl_xor(tmax, 32));
        if (!__all(tmax - m <= 8.0f)) {     // rare: rescale path
            float mn = fmaxf(m, tmax);
            float scale = __builtin_amdgcn_exp2f((m - mn) * 1.44269504f);
            m = mn;
            lsum *= scale;
            float scr[4];
#pragma unroll
            for (int r = 0; r < 4; ++r) scr[r] = __shfl(scale, g4 * 4 + r, 16);
#pragma unroll
            for (int ct = 0; ct < 16; ++ct)
#pragma unroll
                for (int r = 0; r < 4; ++r) acc[ct][r] *= scr[r];
        }
        float psum = 0.f;
        uint pk[4][2];
#pragma unroll
        for (int tt = 0; tt < 4; ++tt) {
            float p0 = __builtin_amdgcn_exp2f((s[tt][0] - m) * 1.44269504f);
            float p1 = __builtin_amdgcn_exp2f((s[tt][1] - m) * 1.44269504f);
            float p2 = __builtin_amdgcn_exp2f((s[tt][2] - m) * 1.44269504f);
            float p3 = __builtin_amdgcn_exp2f((s[tt][3] - m) * 1.44269504f);
            psum += (p0 + p1) + (p2 + p3);
            pk[tt][0] = (uint)f2bf(p0) | ((uint)f2bf(p1) << 16);
            pk[tt][1] = (uint)f2bf(p2) | ((uint)f2bf(p3) << 16);
        }
        psum += __shfl_xor(psum, 16);
        psum += __shfl_xor(psum, 32);
        lsum += psum;
        // ---- P -> per-wave LDS tile (transpose to [q][key]) ----
#pragma unroll
        for (int tt = 0; tt < 4; ++tt) {
            uint2 pv; pv.x = pk[tt][0]; pv.y = pk[tt][1];
            *(uint2*)&lds_p[w][row][tt * 16 + g4 * 4] = pv;
        }
        __builtin_amdgcn_sched_barrier(0);
        asm volatile("s_waitcnt lgkmcnt(0)" ::: "memory");
        __builtin_amdgcn_sched_barrier(0);
        v8s pa0 = *(const v8s*)&lds_p[w][row][g4 * 8];        // keys 0..31
        v8s pa1 = *(const v8s*)&lds_p[w][row][32 + g4 * 8];   // keys 32..63
        // ---- O += P * V  (V B-frags from swizzled LDS) ----
        __builtin_amdgcn_s_setprio(1);
#pragma unroll
        for (int ct = 0; ct < 16; ++ct) {
            int c = ct * 16 + row;
            v8s bv0 = *(const v8s*)(vb + c * 128 + ((g4 ^ (c & 7)) << 4));
            v8s bv1 = *(const v8s*)(vb + c * 128 + (((4 + g4) ^ (c & 7)) << 4));
            acc[ct] = MFMA16(pa0, bv0, acc[ct]);
            acc[ct] = MFMA16(pa1, bv1, acc[ct]);
        }
        __builtin_amdgcn_s_setprio(0);
        __syncthreads();
    }
#undef STAGE

    // ---- epilogue: out = gamma * O/lsum + x ----
    float gm = gamma[0];
    float li[4];
#pragma unroll
    for (int r = 0; r < 4; ++r) li[r] = 1.f / __shfl(lsum, g4 * 4 + r, 16);
#pragma unroll
    for (int ct = 0; ct < 16; ++ct) {
        int c = ct * 16 + row;
#pragma unroll
        for (int r = 0; r < 4; ++r) {
            size_t idx = ((size_t)batch * NTOK + q0 + g4 * 4 + r) * CH + c;
            out[idx] = gm * (acc[ct][r] * li[r]) + x[idx];
        }
    }
}

// ---------------------------------------------------------------------------
extern "C" void kernel_launch(void* const* d_in, const int* in_sizes, int n_in,
                              void* d_out, int out_size, void* d_ws, size_t ws_size,
                              hipStream_t stream) {
    const float* x  = (const float*)d_in[0];
    const float* kf = (const float*)d_in[1];
    const float* kg = (const float*)d_in[2];
    const float* kh = (const float*)d_in[3];
    const float* bf = (const float*)d_in[4];
    const float* bg = (const float*)d_in[5];
    const float* bh = (const float*)d_in[6];
    const float* gm = (const float*)d_in[7];
    float* out = (float*)d_out;

    char* ws = (char*)d_ws;
    ushort* wfT = (ushort*)(ws);                       //  16 KB
    ushort* wgT = (ushort*)(ws + 16384);               //  16 KB
    ushort* whT = (ushort*)(ws + 32768);               // 128 KB
    ushort* fo  = (ushort*)(ws + 163840);              //   2 MB
    ushort* go  = (ushort*)(ws + 163840 + 2097152);    //   2 MB
    ushort* hT  = (ushort*)(ws + 163840 + 4194304);    //  16 MB

    hipLaunchKernelGGL(prep_weights, dim3(256), dim3(256), 0, stream, kf, kg, kh, wfT, wgT, whT);
    hipLaunchKernelGGL(proj_fg, dim3(512), dim3(256), 0, stream, x, wfT, wgT, bf, bg, fo, go);
    hipLaunchKernelGGL(proj_hT, dim3(512, 4), dim3(256), 0, stream, x, whT, bh, hT);
    hipLaunchKernelGGL(flash_attn, dim3(256), dim3(512), 0, stream, fo, go, hT, x, gm, out);
}

// Round 5
// 183.501 us; speedup vs baseline: 3.4074x; 1.1303x over previous
//
#include <hip/hip_runtime.h>
#include <hip/hip_bf16.h>

#define BATCH 8
#define NTOK 4096      // H*W per batch
#define CH 256
#define CF 32
#define KVBLK 64
#define NITER (NTOK / KVBLK)

typedef float v4f __attribute__((ext_vector_type(4)));
typedef short v8s __attribute__((ext_vector_type(8)));

static __device__ __forceinline__ ushort f2bf(float f) {
    union { float f; uint u; } v; v.f = f;
    uint u = v.u;
    uint r = (u + 0x7fffu + ((u >> 16) & 1u)) >> 16;   // round-nearest-even
    return (ushort)r;
}

static __device__ __forceinline__ uint cvt_pk(float lo, float hi) {
    uint r;
    asm("v_cvt_pk_bf16_f32 %0, %1, %2" : "=v"(r) : "v"(lo), "v"(hi));
    return r;
}

static __device__ __forceinline__ void gload16(const void* g, void* l) {
    __builtin_amdgcn_global_load_lds(
        (const __attribute__((address_space(1))) unsigned int*)g,
        (__attribute__((address_space(3))) unsigned int*)l, 16, 0, 0);
}

#define MFMA16(a, b, c) __builtin_amdgcn_mfma_f32_16x16x32_bf16(a, b, c, 0, 0, 0)

// ---------------------------------------------------------------------------
// Kernel 1: transpose + cast weights to bf16 via LDS tiles (coalesced both ways)
// grid 40: bid<32 -> kh (64k x 32c tiles); 32-35 -> kf; 36-39 -> kg
// ---------------------------------------------------------------------------
__global__ __launch_bounds__(256) void prep_weights(
    const float* __restrict__ kf, const float* __restrict__ kg,
    const float* __restrict__ kh,
    ushort* __restrict__ wfT, ushort* __restrict__ wgT, ushort* __restrict__ whT) {
    __shared__ float tile[64][33];
    int bid = blockIdx.x;
    const float* src; ushort* dst; int cols, k0, c0;
    if (bid < 32)      { src = kh; dst = whT; cols = 256; k0 = (bid >> 3) * 64; c0 = (bid & 7) * 32; }
    else if (bid < 36) { src = kf; dst = wfT; cols = 32;  k0 = (bid - 32) * 64; c0 = 0; }
    else               { src = kg; dst = wgT; cols = 32;  k0 = (bid - 36) * 64; c0 = 0; }
    int t = threadIdx.x;
    int kr = t >> 2, cb = (t & 3) * 8;
#pragma unroll
    for (int j = 0; j < 8; ++j) tile[kr][cb + j] = src[(size_t)(k0 + kr) * cols + c0 + cb + j];
    __syncthreads();
    int c = t >> 3, kc = (t & 7) * 8;
    ushort tmp[8];
#pragma unroll
    for (int j = 0; j < 8; ++j) tmp[j] = f2bf(tile[kc + j][c]);
    *(uint4*)(dst + (size_t)(c0 + c) * CH + k0 + kc) = *(uint4*)tmp;
}

// ---------------------------------------------------------------------------
// Kernel 2: fused projections.  Per block (512 thr, 8 waves): one 64-n tile.
// x-tile staged once as swizzled bf16 in LDS; same fragments feed:
//   hT[c][n] (wave w: c in [w*32, w*32+32), all 64 n)   [A=whT rows, B=x rows]
//   f (waves 0-3, ntile=w) / g (waves 4-7, ntile=w&3)   [A=x rows, B=wfT/wgT]
// ---------------------------------------------------------------------------
__global__ __launch_bounds__(512) void proj_all(
    const float* __restrict__ x, const ushort* __restrict__ wfT,
    const ushort* __restrict__ wgT, const ushort* __restrict__ whT,
    const float* __restrict__ bf, const float* __restrict__ bg,
    const float* __restrict__ bh,
    ushort* __restrict__ fo, ushort* __restrict__ go, ushort* __restrict__ hT) {
    __shared__ __align__(16) ushort xl[64 * 256];   // 32 KB, 16B-chunk swizzle ^(n&7)
    int tid = threadIdx.x;
    int lane = tid & 63, w = tid >> 6;
    int row = lane & 15, g4 = lane >> 4;
    int n0 = blockIdx.x * 64;

    // ---- stage x -> bf16 LDS (chunk cc of row n at chunk-slot cc^(n&7)) ----
#pragma unroll
    for (int i = 0; i < 4; ++i) {
        int id = i * 512 + tid;          // 2048 chunks of 16 B
        int n = id >> 5, cc = id & 31;
        const float* xp = x + (size_t)(n0 + n) * CH + cc * 8;
        float4 a0 = ((const float4*)xp)[0], a1 = ((const float4*)xp)[1];
        uint4 pv;
        pv.x = cvt_pk(a0.x, a0.y); pv.y = cvt_pk(a0.z, a0.w);
        pv.z = cvt_pk(a1.x, a1.y); pv.w = cvt_pk(a1.z, a1.w);
        *(uint4*)((char*)xl + n * 512 + ((cc ^ (n & 7)) << 4)) = pv;
    }
    __syncthreads();

    int c0 = w * 32;
    int myNt = w & 3;
    const ushort* wpT = (w < 4) ? wfT : wgT;

    v4f acch[2][4] = {};
    v4f accp[2] = {};
    for (int ks = 0; ks < 8; ++ks) {
        v8s xf[4];
#pragma unroll
        for (int nt = 0; nt < 4; ++nt) {
            int n = nt * 16 + row;
            int ch = (ks * 4 + g4) ^ (n & 7);
            xf[nt] = *(const v8s*)((char*)xl + n * 512 + (ch << 4));
        }
        v8s wh0 = *(const v8s*)(whT + (size_t)(c0 + row) * CH + ks * 32 + g4 * 8);
        v8s wh1 = *(const v8s*)(whT + (size_t)(c0 + 16 + row) * CH + ks * 32 + g4 * 8);
#pragma unroll
        for (int nt = 0; nt < 4; ++nt) {
            acch[0][nt] = MFMA16(wh0, xf[nt], acch[0][nt]);
            acch[1][nt] = MFMA16(wh1, xf[nt], acch[1][nt]);
        }
        v8s wp0 = *(const v8s*)(wpT + (size_t)row * CH + ks * 32 + g4 * 8);
        v8s wp1 = *(const v8s*)(wpT + (size_t)(16 + row) * CH + ks * 32 + g4 * 8);
        accp[0] = MFMA16(xf[myNt], wp0, accp[0]);
        accp[1] = MFMA16(xf[myNt], wp1, accp[1]);
    }

    // ---- hT epilogue: hT[c][n], lanes -> consecutive n (coalesced) ----
    int batch = n0 >> 12;
    int nn0 = n0 & (NTOK - 1);
    ushort* hTb = hT + (size_t)batch * CH * NTOK;
#pragma unroll
    for (int ct = 0; ct < 2; ++ct)
#pragma unroll
        for (int r = 0; r < 4; ++r) {
            int c = c0 + ct * 16 + g4 * 4 + r;
            float bias = bh[c];
#pragma unroll
            for (int nt = 0; nt < 4; ++nt)
                hTb[(size_t)c * NTOK + nn0 + nt * 16 + row] = f2bf(acch[ct][nt][r] + bias);
        }
    // ---- f/g epilogue ----
    const float* bp = (w < 4) ? bf : bg;
    ushort* po = (w < 4) ? fo : go;
#pragma unroll
    for (int ct = 0; ct < 2; ++ct)
#pragma unroll
        for (int r = 0; r < 4; ++r) {
            int n = n0 + myNt * 16 + g4 * 4 + r;
            int cf = ct * 16 + row;
            po[(size_t)n * CF + cf] = f2bf(accp[ct][r] + bp[cf]);
        }
}

// ---------------------------------------------------------------------------
// Kernel 3: flash attention, LDS-staged + double-buffered + defer-max.
// 512 thr = 8 waves x 16 q = 128 q per block; grid 256 (1 block/CU).
// LDS read addresses hoisted: swizzles are iteration/tile-invariant.
// ---------------------------------------------------------------------------
__global__ __launch_bounds__(512, 2) void flash_attn(
    const ushort* __restrict__ fbuf, const ushort* __restrict__ gbuf,
    const ushort* __restrict__ hT, const float* __restrict__ x,
    const float* __restrict__ gamma, float* __restrict__ out) {
    __shared__ __align__(16) ushort lds_f[2][2048];    //  8 KB total
    __shared__ __align__(16) ushort lds_v[2][16384];   // 64 KB total
    __shared__ __align__(16) ushort lds_p[8][16][88];  // 22.5 KB

    int tid = threadIdx.x;
    int lane = tid & 63, w = tid >> 6;
    int row = lane & 15, g4 = lane >> 4;
    int batch = blockIdx.x & 7;
    int q0 = (blockIdx.x >> 3) * 128 + w * 16;

    const ushort* fB = fbuf + (size_t)batch * NTOK * CF;
    const ushort* gB = gbuf + (size_t)batch * NTOK * CF;
    const ushort* hB = hT + (size_t)batch * CH * NTOK;

#define STAGE(buf, kb) do {                                                     \
        _Pragma("unroll")                                                       \
        for (int i_ = 0; i_ < 4; ++i_) {                                        \
            int g_ = i_ * 512 + tid;                                            \
            int c_ = g_ >> 3, ch_ = g_ & 7;                                     \
            const ushort* s_ = hB + (size_t)c_ * NTOK + (kb) + ((ch_ ^ (c_ & 7)) << 3); \
            gload16(s_, (char*)&lds_v[buf][0] + g_ * 16);                       \
        }                                                                       \
        if (tid < 256) {                                                        \
            int k_ = tid >> 2, ch_ = tid & 3;                                   \
            const ushort* s_ = fB + (size_t)((kb) + k_) * CF + ((ch_ ^ ((k_ >> 1) & 3)) << 3); \
            gload16(s_, (char*)&lds_f[buf][0] + tid * 16);                      \
        }                                                                       \
    } while (0)

    // hoisted LDS read bases (swizzles invariant across iters/tiles)
    const int vswz0 = (g4 ^ (row & 7)) << 4;
    const int vswz1 = ((4 + g4) ^ (row & 7)) << 4;
    const int fswz  = (g4 ^ ((row >> 1) & 3)) << 4;
    const char* vA0 = (const char*)&lds_v[0][0] + row * 128 + vswz0;
    const char* vA1 = (const char*)&lds_v[1][0] + row * 128 + vswz0;
    const char* vB0 = (const char*)&lds_v[0][0] + row * 128 + vswz1;
    const char* vB1 = (const char*)&lds_v[1][0] + row * 128 + vswz1;
    const char* fA0 = (const char*)&lds_f[0][0] + row * 64 + fswz;
    const char* fA1 = (const char*)&lds_f[1][0] + row * 64 + fswz;

    // Q^T B-fragment, lives across the whole loop
    v8s bq = *(const v8s*)(gB + (size_t)(q0 + row) * CF + g4 * 8);

    float m = -1e30f, lsum = 0.f;
    v4f acc[16] = {};   // O tile: 16 q x 256 c
    const v4f vzero = {};

    STAGE(0, 0);
    __syncthreads();

    for (int t = 0; t < NITER; ++t) {
        int cur = t & 1;
        if (t + 1 < NITER) STAGE(cur ^ 1, (t + 1) * KVBLK);

        const v8s* fA = (const v8s*)(cur ? fA1 : fA0);
        const v8s* vA = (const v8s*)(cur ? vA1 : vA0);
        const v8s* vB = (const v8s*)(cur ? vB1 : vB0);

        // ---- S^T tiles: 4 x (16 key x 16 q) ----
        v4f s[4];
#pragma unroll
        for (int tt = 0; tt < 4; ++tt)
            s[tt] = MFMA16(fA[tt * 64], bq, vzero);
        // ---- online softmax with defer-max (state per q = lane&15) ----
        float tmax = -1e30f;
#pragma unroll
        for (int tt = 0; tt < 4; ++tt)
#pragma unroll
            for (int r = 0; r < 4; ++r) tmax = fmaxf(tmax, s[tt][r]);
        tmax = fmaxf(tmax, __shfl_xor(tmax, 16));
        tmax = fmaxf(tmax, __shfl_xor(tmax, 32));
        if (!__all(tmax - m <= 8.0f)) {     // rare: rescale path
            float mn = fmaxf(m, tmax);
            float scale = __builtin_amdgcn_exp2f((m - mn) * 1.44269504f);
            m = mn;
            lsum *= scale;
            float scr[4];
#pragma unroll
            for (int r = 0; r < 4; ++r) scr[r] = __shfl(scale, g4 * 4 + r, 16);
#pragma unroll
            for (int ct = 0; ct < 16; ++ct)
#pragma unroll
                for (int r = 0; r < 4; ++r) acc[ct][r] *= scr[r];
        }
        float psum = 0.f;
        uint pk[4][2];
#pragma unroll
        for (int tt = 0; tt < 4; ++tt) {
            float p0 = __builtin_amdgcn_exp2f((s[tt][0] - m) * 1.44269504f);
            float p1 = __builtin_amdgcn_exp2f((s[tt][1] - m) * 1.44269504f);
            float p2 = __builtin_amdgcn_exp2f((s[tt][2] - m) * 1.44269504f);
            float p3 = __builtin_amdgcn_exp2f((s[tt][3] - m) * 1.44269504f);
            psum += (p0 + p1) + (p2 + p3);
            pk[tt][0] = cvt_pk(p0, p1);
            pk[tt][1] = cvt_pk(p2, p3);
        }
        psum += __shfl_xor(psum, 16);
        psum += __shfl_xor(psum, 32);
        lsum += psum;
        // ---- P -> per-wave LDS tile (transpose to [q][key]) ----
#pragma unroll
        for (int tt = 0; tt < 4; ++tt) {
            uint2 pv; pv.x = pk[tt][0]; pv.y = pk[tt][1];
            *(uint2*)&lds_p[w][row][tt * 16 + g4 * 4] = pv;
        }
        __builtin_amdgcn_sched_barrier(0);
        asm volatile("s_waitcnt lgkmcnt(0)" ::: "memory");
        __builtin_amdgcn_sched_barrier(0);
        v8s pa0 = *(const v8s*)&lds_p[w][row][g4 * 8];        // keys 0..31
        v8s pa1 = *(const v8s*)&lds_p[w][row][32 + g4 * 8];   // keys 32..63
        // ---- O += P * V ----
        __builtin_amdgcn_s_setprio(1);
#pragma unroll
        for (int ct = 0; ct < 16; ++ct) {
            acc[ct] = MFMA16(pa0, vA[ct * 128], acc[ct]);
            acc[ct] = MFMA16(pa1, vB[ct * 128], acc[ct]);
        }
        __builtin_amdgcn_s_setprio(0);
        __syncthreads();
    }
#undef STAGE

    // ---- epilogue: out = gamma * O/lsum + x ----
    float gm = gamma[0];
    float li[4];
#pragma unroll
    for (int r = 0; r < 4; ++r) li[r] = 1.f / __shfl(lsum, g4 * 4 + r, 16);
#pragma unroll
    for (int ct = 0; ct < 16; ++ct) {
        int c = ct * 16 + row;
#pragma unroll
        for (int r = 0; r < 4; ++r) {
            size_t idx = ((size_t)batch * NTOK + q0 + g4 * 4 + r) * CH + c;
            out[idx] = gm * (acc[ct][r] * li[r]) + x[idx];
        }
    }
}

// ---------------------------------------------------------------------------
extern "C" void kernel_launch(void* const* d_in, const int* in_sizes, int n_in,
                              void* d_out, int out_size, void* d_ws, size_t ws_size,
                              hipStream_t stream) {
    const float* x  = (const float*)d_in[0];
    const float* kf = (const float*)d_in[1];
    const float* kg = (const float*)d_in[2];
    const float* kh = (const float*)d_in[3];
    const float* bf = (const float*)d_in[4];
    const float* bg = (const float*)d_in[5];
    const float* bh = (const float*)d_in[6];
    const float* gm = (const float*)d_in[7];
    float* out = (float*)d_out;

    char* ws = (char*)d_ws;
    ushort* wfT = (ushort*)(ws);                       //  16 KB
    ushort* wgT = (ushort*)(ws + 16384);               //  16 KB
    ushort* whT = (ushort*)(ws + 32768);               // 128 KB
    ushort* fo  = (ushort*)(ws + 163840);              //   2 MB
    ushort* go  = (ushort*)(ws + 163840 + 2097152);    //   2 MB
    ushort* hT  = (ushort*)(ws + 163840 + 4194304);    //  16 MB

    hipLaunchKernelGGL(prep_weights, dim3(40), dim3(256), 0, stream, kf, kg, kh, wfT, wgT, whT);
    hipLaunchKernelGGL(proj_all, dim3(512), dim3(512), 0, stream,
                       x, wfT, wgT, whT, bf, bg, bh, fo, go, hT);
    hipLaunchKernelGGL(flash_attn, dim3(256), dim3(512), 0, stream, fo, go, hT, x, gm, out);
}